// Round 2
// 116.658 us; speedup vs baseline: 1.7038x; 1.7038x over previous
//
#include <hip/hip_runtime.h>
#include <math.h>

// ================== problem constants ==================
#define BATCH   4096
#define NPUMP   4
#define NCH     100
#define RESPLEN 801

// RK4: 32 steps over 50 km (validated rung from prior session; absmax
// 1.22e-4 = fp16-ulp-pinned vs threshold 2.11e-4).
#define NSTEPS  32
#define DZ_F    1562.5f
#define HDZ_F   781.25f
#define DZ6_F   260.4166666666667f
#define LOSSC   4.605170185988092e-05f   // 0.0002 * ln(10)/10
#define INV256  0.00390625f              // undo the 2^8 G pre-scale

// ================== structure ==========================
// 16 batch elements per block (= MFMA N). 4 waves:
//   waves 0..2: signal rows via mfma_f32_16x16x32_f16, NT=3 row-tiles each
//               (tiles rbase=wid*3 .. +2; tiles with rows>=100 are zero/dummy)
//   wave  3   : the 4 batch-specific pump rows via v_dot2 (52 dot2/lane)
// P vector staged in LDS as fp16, column-major per batch, double-buffered.
#define GB      16
#define ROWSTR  136   // f16 rows per column = 272 B stride: 16B-aligned and
                      // 68 dwords == 4 (mod 32) -> conflict-free b128 reads
#define NT      3

typedef _Float16 f16;
typedef _Float16 f16x2 __attribute__((ext_vector_type(2)));
typedef _Float16 f16x8 __attribute__((ext_vector_type(8)));
typedef float    f32x4 __attribute__((ext_vector_type(4)));

// Gain entry, scaled by 256 (3.2e12 = 1.25e10 * 2^8) so fp16-quantized
// near-diagonal entries stay normal. Consumers multiply y by INV256.
__device__ __forceinline__ float gentry(float fi, float fj, float invfj,
                                        const float* __restrict__ resp_s)
{
    float D    = fj - fi;
    float ad   = fabsf(D);
    float fidx = ad * 2.0e-11f;          // 1/DF
    int   i0   = (int)fidx;
    i0 = i0 > (RESPLEN - 2) ? (RESPLEN - 2) : i0;
    float w  = fidx - (float)i0;
    float g  = resp_s[i0] * (1.0f - w) + resp_s[i0 + 1] * w;
    g = (D < 0.0f) ? -g : g;
    float ratio = fi * invfj;
    float m  = fmaxf(1.0f, ratio);
    return g * m * 3.2e12f;              // (1/EFFECTIVE_AREA) * 256
}

// One RK stage. Reads P (fp16) from Pls[buf], writes next-stage P to
// Pls[buf^1], one barrier. FIRST_/LAST_ are 0/1 literals.
#define STAGE(A_, W_, FIRST_, LAST_)                                           \
  {                                                                            \
    const f16* pb = (const f16*)&Pls[buf][c][0];                               \
    if (wid == 3) {                                                            \
      float yp0 = 0.0f, yp1 = 0.0f, yp2 = 0.0f, yp3 = 0.0f;                    \
      _Pragma("unroll")                                                        \
      for (int mb = 0; mb < 13; ++mb) {                                        \
        union { f16x8 v; f16x2 h[4]; } u;                                      \
        u.v = *(const f16x8*)(pb + 8 * mb);                                    \
        yp0 = __builtin_amdgcn_fdot2(gpr[4 * mb + 0], u.h[0], yp0, false);     \
        yp1 = __builtin_amdgcn_fdot2(gpr[4 * mb + 1], u.h[1], yp1, false);     \
        yp2 = __builtin_amdgcn_fdot2(gpr[4 * mb + 2], u.h[2], yp2, false);     \
        yp3 = __builtin_amdgcn_fdot2(gpr[4 * mb + 3], u.h[3], yp3, false);     \
      }                                                                        \
      float ypt = (yp0 + yp1) + (yp2 + yp3);                                   \
      float kp  = fmaf(ypt, INV256, -LOSSC) * sp;                              \
      if (FIRST_) kps = kp; else kps += (W_) * kp;                             \
      if (LAST_) { P0p += DZ6_F * kps; sp = P0p; }                             \
      else       { sp = fmaf((A_), kp, P0p); }                                 \
      Pls[buf ^ 1][c][NCH + q] = (f16)sp;                                      \
    } else {                                                                   \
      const f16x8 B0 = *(const f16x8*)(pb + 8 * q);                            \
      const f16x8 B1 = *(const f16x8*)(pb + 32 + 8 * q);                       \
      const f16x8 B2 = *(const f16x8*)(pb + 64 + 8 * q);                       \
      const f16x8 B3 = *(const f16x8*)(pb + 96 + 8 * q);                       \
      const f16x2 pp0 = *(const f16x2*)(pb + 100);                             \
      const f16x2 pp1 = *(const f16x2*)(pb + 102);                             \
      _Pragma("unroll")                                                        \
      for (int rt = 0; rt < NT; ++rt) {                                        \
        f32x4 a = {0.0f, 0.0f, 0.0f, 0.0f};                                    \
        a = __builtin_amdgcn_mfma_f32_16x16x32_f16(Af[rt][0], B0, a, 0, 0, 0); \
        a = __builtin_amdgcn_mfma_f32_16x16x32_f16(Af[rt][1], B1, a, 0, 0, 0); \
        a = __builtin_amdgcn_mfma_f32_16x16x32_f16(Af[rt][2], B2, a, 0, 0, 0); \
        a = __builtin_amdgcn_mfma_f32_16x16x32_f16(Af[rt][3], B3, a, 0, 0, 0); \
        _Pragma("unroll")                                                      \
        for (int m = 0; m < 4; ++m) {                                          \
          float y = a[m];                                                      \
          y = __builtin_amdgcn_fdot2(gp01[rt][m], pp0, y, false);              \
          y = __builtin_amdgcn_fdot2(gp23[rt][m], pp1, y, false);              \
          float kk = fmaf(y, INV256, -LOSSC) * sv[rt][m];                      \
          if (FIRST_) ks[rt][m] = kk; else ks[rt][m] += (W_) * kk;             \
          if (LAST_) { P0v[rt][m] += DZ6_F * ks[rt][m]; sv[rt][m] = P0v[rt][m]; } \
          else       { sv[rt][m] = fmaf((A_), kk, P0v[rt][m]); }               \
        }                                                                      \
      }                                                                        \
      _Pragma("unroll")                                                        \
      for (int rt = 0; rt < NT; ++rt) {                                        \
        const int row0w = 16 * (wid * NT + rt) + 4 * q;                        \
        if (row0w < NCH) {                                                     \
          union { f16x2 h[2]; uint2 u2; } cv;                                  \
          cv.h[0] = f16x2{(f16)sv[rt][0], (f16)sv[rt][1]};                     \
          cv.h[1] = f16x2{(f16)sv[rt][2], (f16)sv[rt][3]};                     \
          *(uint2*)&Pls[buf ^ 1][c][row0w] = cv.u2;                            \
        }                                                                      \
      }                                                                        \
    }                                                                          \
    __syncthreads();                                                           \
    buf ^= 1;                                                                  \
  }

__global__ __launch_bounds__(256, 1)
void raman_kernel(const float* __restrict__ x,       // (BATCH, 8)
                  const float* __restrict__ resp,    // (801,)
                  const float* __restrict__ sigwl,   // (100,)
                  float* __restrict__ out)           // (BATCH, 100)
{
    // P: rows 0..99 = signal channels, 100..103 = pumps, 104..135 = zero pad
    __shared__ __align__(16) f16 Pls[2][GB][ROWSTR];
    __shared__ float resp_s[RESPLEN + 3];
    __shared__ float sigf[NCH], siginv[NCH];
    __shared__ float pf[GB][NPUMP], pinv[GB][NPUMP], ppw[GB][NPUMP];

    const int tid  = threadIdx.x;
    const int wid  = tid >> 6;
    const int lane = tid & 63;
    const int c    = lane & 15;   // batch column; also A-row-within-tile
    const int q    = lane >> 4;   // quad index (k-group / C-row-group)
    const int b0   = blockIdx.x * GB;

    for (int i = tid; i < RESPLEN; i += 256) resp_s[i] = resp[i];
    for (int i = tid; i < NCH; i += 256) {
        float lam = sigwl[i];
        sigf[i]   = 299792458.0f / lam;
        siginv[i] = lam * 3.3356409519815204e-09f;   // lam/C0
    }
    if (tid < GB * NPUMP) {
        const int cc = tid >> 2, p = tid & 3;
        float lam = x[(b0 + cc) * 8 + p];
        pf[cc][p]   = 299792458.0f / lam;
        pinv[cc][p] = lam * 3.3356409519815204e-09f;
        ppw[cc][p]  = fabsf(x[(b0 + cc) * 8 + NPUMP + p]);
    }
    {   // zero both P buffers (incl. pad rows; pads are never rewritten)
        f16* pz = (f16*)Pls;
        for (int i = tid; i < 2 * GB * ROWSTR; i += 256) pz[i] = (f16)0.0f;
    }
    __syncthreads();

    // ---- A fragments: shared signal-signal gain block (fp16, x256) ----
    // v_mfma_f32_16x16x32_f16: A[row][k]: row = lane%16, k = 8*(lane/16)+j
    f16x8 Af[NT][4];
    #pragma unroll
    for (int rt = 0; rt < NT; ++rt) {
        const int row = 16 * (wid * NT + rt) + c;
        const float fi = (row < NCH) ? sigf[row] : 0.0f;
        #pragma unroll
        for (int t = 0; t < 4; ++t) {
            f16x8 a;
            #pragma unroll
            for (int j = 0; j < 8; ++j) {
                const int k = 32 * t + 8 * q + j;
                float v = 0.0f;
                // pump columns (k>=100) excluded: added via gp01/gp23 dot2s
                if (row < NCH && k < NCH)
                    v = gentry(fi, sigf[k], siginv[k], resp_s);
                a[j] = (f16)v;
            }
            Af[rt][t] = a;
        }
    }

    // ---- G_sp: batch-specific pump columns for owned C elements ----
    // C/D: col = lane&15 (=batch c), row = 16*tile + 4*q + m
    f16x2 gp01[NT][4], gp23[NT][4];
    #pragma unroll
    for (int rt = 0; rt < NT; ++rt) {
        #pragma unroll
        for (int m = 0; m < 4; ++m) {
            const int row = 16 * (wid * NT + rt) + 4 * q + m;
            float v0 = 0.0f, v1 = 0.0f, v2 = 0.0f, v3 = 0.0f;
            if (row < NCH) {
                const float fi = sigf[row];
                v0 = gentry(fi, pf[c][0], pinv[c][0], resp_s);
                v1 = gentry(fi, pf[c][1], pinv[c][1], resp_s);
                v2 = gentry(fi, pf[c][2], pinv[c][2], resp_s);
                v3 = gentry(fi, pf[c][3], pinv[c][3], resp_s);
            }
            gp01[rt][m] = f16x2{(f16)v0, (f16)v1};
            gp23[rt][m] = f16x2{(f16)v2, (f16)v3};
        }
    }

    // ---- pump-row gain vectors (wave 3: lane (c,q) -> pump row q, batch c)
    f16x2 gpr[52];
    float P0p = 0.0f, sp = 0.0f, kps = 0.0f;
    if (wid == 3) {
        const float fi = pf[c][q];
        #pragma unroll
        for (int d = 0; d < 52; ++d) {
            const int j0 = 2 * d, j1 = 2 * d + 1;
            float f0 = (j0 < NCH) ? sigf[j0]   : pf[c][j0 - NCH];
            float w0 = (j0 < NCH) ? siginv[j0] : pinv[c][j0 - NCH];
            float f1 = (j1 < NCH) ? sigf[j1]   : pf[c][j1 - NCH];
            float w1 = (j1 < NCH) ? siginv[j1] : pinv[c][j1 - NCH];
            gpr[d] = f16x2{(f16)gentry(fi, f0, w0, resp_s),
                           (f16)gentry(fi, f1, w1, resp_s)};
        }
        P0p = ppw[c][q];
        sp  = P0p;
    }

    // ---- state init (f32, C-layout) + initial P into buffer 0 ----
    float P0v[NT][4], sv[NT][4], ks[NT][4];
    #pragma unroll
    for (int rt = 0; rt < NT; ++rt)
        #pragma unroll
        for (int m = 0; m < 4; ++m) {
            const int row = 16 * (wid * NT + rt) + 4 * q + m;
            P0v[rt][m] = (row < NCH) ? 1.0e-3f : 0.0f;
            sv[rt][m]  = P0v[rt][m];
            ks[rt][m]  = 0.0f;
        }

    int buf = 0;
    #pragma unroll
    for (int rt = 0; rt < NT; ++rt) {
        const int row0 = 16 * (wid * NT + rt) + 4 * q;
        if (row0 < NCH) {
            union { f16x2 h[2]; uint2 u2; } cv;
            cv.h[0] = f16x2{(f16)sv[rt][0], (f16)sv[rt][1]};
            cv.h[1] = f16x2{(f16)sv[rt][2], (f16)sv[rt][3]};
            *(uint2*)&Pls[0][c][row0] = cv.u2;
        }
    }
    if (wid == 3) Pls[0][c][NCH + q] = (f16)sp;
    __syncthreads();

    // ---- RK4 main loop: 32 steps x 4 stages, 1 barrier per stage ----
    #pragma unroll 1
    for (int step = 0; step < NSTEPS; ++step) {
        STAGE(HDZ_F, 1.0f, 1, 0)   // k1
        STAGE(HDZ_F, 2.0f, 0, 0)   // k2
        STAGE(DZ_F,  2.0f, 0, 0)   // k3
        STAGE(0.0f,  1.0f, 0, 1)   // k4 + P0 += dz/6 * ksum
    }

    // ---- output: signal rows 0..99 (float4, 16B-aligned: 400 = 25*16) ----
    #pragma unroll
    for (int rt = 0; rt < NT; ++rt) {
        const int row0 = 16 * (wid * NT + rt) + 4 * q;
        if (row0 < NCH) {
            float4 o = make_float4(P0v[rt][0], P0v[rt][1],
                                   P0v[rt][2], P0v[rt][3]);
            *(float4*)&out[(b0 + c) * NCH + row0] = o;
        }
    }
}

extern "C" void kernel_launch(void* const* d_in, const int* in_sizes, int n_in,
                              void* d_out, int out_size, void* d_ws, size_t ws_size,
                              hipStream_t stream)
{
    const float* x     = (const float*)d_in[0];
    const float* resp  = (const float*)d_in[1];
    const float* sigwl = (const float*)d_in[2];
    float* out = (float*)d_out;
    raman_kernel<<<BATCH / GB, 256, 0, stream>>>(x, resp, sigwl, out);
}

// Round 3
// 111.079 us; speedup vs baseline: 1.7894x; 1.0502x over previous
//
#include <hip/hip_runtime.h>
#include <math.h>

// ================== problem constants ==================
#define BATCH   4096
#define NPUMP   4
#define NCH     100
#define RESPLEN 801

// RK4: 32 steps over 50 km (validated: absmax 1.22e-4 vs threshold 2.11e-4).
#define NSTEPS  32
#define DZ_F    1562.5f
#define HDZ_F   781.25f
#define DZ6_F   260.4166666666667f
#define LOSSC   4.605170185988092e-05f   // 0.0002 * ln(10)/10
#define INV256  0.00390625f              // undo the 2^8 G pre-scale

// ================== structure ==========================
// 16 batch elements per block (= MFMA N). 8 waves (512 thr) -> 2 waves/SIMD:
//   waves 0..6: ONE 16-row signal tile each (rows 16*wid .. 16*wid+15) via
//               mfma_f32_16x16x32_f16 (two 2-deep accumulator chains)
//   wave  7   : the 4 batch-specific pump rows via v_dot2 (52 dot2/lane)
// P vector staged in LDS as fp16, column-major per batch, double-buffered.
#define GB      16
#define ROWSTR  136   // f16 rows per column = 272 B stride (16B-aligned)

typedef _Float16 f16;
typedef _Float16 f16x2 __attribute__((ext_vector_type(2)));
typedef _Float16 f16x8 __attribute__((ext_vector_type(8)));
typedef float    f32x4 __attribute__((ext_vector_type(4)));

// Gain entry, scaled by 256 (3.2e12 = 1.25e10 * 2^8) so fp16-quantized
// near-diagonal entries stay normal. Consumers multiply y by INV256.
__device__ __forceinline__ float gentry(float fi, float fj, float invfj,
                                        const float* __restrict__ resp_s)
{
    float D    = fj - fi;
    float ad   = fabsf(D);
    float fidx = ad * 2.0e-11f;          // 1/DF
    int   i0   = (int)fidx;
    i0 = i0 > (RESPLEN - 2) ? (RESPLEN - 2) : i0;
    float w  = fidx - (float)i0;
    float g  = resp_s[i0] * (1.0f - w) + resp_s[i0 + 1] * w;
    g = (D < 0.0f) ? -g : g;
    float ratio = fi * invfj;
    float m  = fmaxf(1.0f, ratio);
    return g * m * 3.2e12f;              // (1/EFFECTIVE_AREA) * 256
}

// One RK stage. Reads P (fp16) from Pls[buf], writes next-stage P to
// Pls[buf^1], one barrier. FIRST_/LAST_ are 0/1 literals.
#define STAGE(A_, W_, FIRST_, LAST_)                                           \
  {                                                                            \
    const f16* pb = (const f16*)&Pls[buf][c][0];                               \
    if (wid == 7) {                                                            \
      float yp0 = 0.0f, yp1 = 0.0f, yp2 = 0.0f, yp3 = 0.0f;                    \
      _Pragma("unroll")                                                        \
      for (int mb = 0; mb < 13; ++mb) {                                        \
        union { f16x8 v; f16x2 h[4]; } u;                                      \
        u.v = *(const f16x8*)(pb + 8 * mb);                                    \
        yp0 = __builtin_amdgcn_fdot2(gpr[4 * mb + 0], u.h[0], yp0, false);     \
        yp1 = __builtin_amdgcn_fdot2(gpr[4 * mb + 1], u.h[1], yp1, false);     \
        yp2 = __builtin_amdgcn_fdot2(gpr[4 * mb + 2], u.h[2], yp2, false);     \
        yp3 = __builtin_amdgcn_fdot2(gpr[4 * mb + 3], u.h[3], yp3, false);     \
      }                                                                        \
      float ypt = (yp0 + yp1) + (yp2 + yp3);                                   \
      float kp  = fmaf(ypt, INV256, -LOSSC) * sp;                              \
      if (FIRST_) kps = kp; else kps += (W_) * kp;                             \
      if (LAST_) { P0p += DZ6_F * kps; sp = P0p; }                             \
      else       { sp = fmaf((A_), kp, P0p); }                                 \
      Pls[buf ^ 1][c][NCH + q] = (f16)sp;                                      \
    } else {                                                                   \
      const f16x8 B0 = *(const f16x8*)(pb + 8 * q);                            \
      const f16x8 B1 = *(const f16x8*)(pb + 32 + 8 * q);                       \
      const f16x8 B2 = *(const f16x8*)(pb + 64 + 8 * q);                       \
      const f16x8 B3 = *(const f16x8*)(pb + 96 + 8 * q);                       \
      union { uint2 u2; f16x2 h[2]; } ppu;                                     \
      ppu.u2 = *(const uint2*)(pb + 100);                                      \
      f32x4 a01 = {0.0f, 0.0f, 0.0f, 0.0f};                                    \
      f32x4 a23 = {0.0f, 0.0f, 0.0f, 0.0f};                                    \
      a01 = __builtin_amdgcn_mfma_f32_16x16x32_f16(Af0, B0, a01, 0, 0, 0);     \
      a23 = __builtin_amdgcn_mfma_f32_16x16x32_f16(Af1, B1, a23, 0, 0, 0);     \
      a01 = __builtin_amdgcn_mfma_f32_16x16x32_f16(Af2, B2, a01, 0, 0, 0);     \
      a23 = __builtin_amdgcn_mfma_f32_16x16x32_f16(Af3, B3, a23, 0, 0, 0);     \
      _Pragma("unroll")                                                        \
      for (int m = 0; m < 4; ++m) {                                            \
        float y = a01[m] + a23[m];                                             \
        y = __builtin_amdgcn_fdot2(gp01[m], ppu.h[0], y, false);               \
        y = __builtin_amdgcn_fdot2(gp23[m], ppu.h[1], y, false);               \
        float kk = fmaf(y, INV256, -LOSSC) * sv[m];                            \
        if (FIRST_) ks[m] = kk; else ks[m] += (W_) * kk;                       \
        if (LAST_) { P0v[m] += DZ6_F * ks[m]; sv[m] = P0v[m]; }                \
        else       { sv[m] = fmaf((A_), kk, P0v[m]); }                         \
      }                                                                        \
      if (row0 < NCH) {                                                        \
        union { f16x2 h[2]; uint2 u2; } cv;                                    \
        cv.h[0] = f16x2{(f16)sv[0], (f16)sv[1]};                               \
        cv.h[1] = f16x2{(f16)sv[2], (f16)sv[3]};                               \
        *(uint2*)&Pls[buf ^ 1][c][row0] = cv.u2;                               \
      }                                                                        \
    }                                                                          \
    __syncthreads();                                                           \
    buf ^= 1;                                                                  \
  }

__global__ __launch_bounds__(512, 1)
void raman_kernel(const float* __restrict__ x,       // (BATCH, 8)
                  const float* __restrict__ resp,    // (801,)
                  const float* __restrict__ sigwl,   // (100,)
                  float* __restrict__ out)           // (BATCH, 100)
{
    // P: rows 0..99 = signal channels, 100..103 = pumps, 104..135 = zero pad
    __shared__ __align__(16) f16 Pls[2][GB][ROWSTR];
    __shared__ float resp_s[RESPLEN + 3];
    __shared__ float sigf[NCH], siginv[NCH];
    __shared__ float pf[GB][NPUMP], pinv[GB][NPUMP], ppw[GB][NPUMP];

    const int tid  = threadIdx.x;
    const int wid  = tid >> 6;
    const int lane = tid & 63;
    const int c    = lane & 15;   // batch column; also A-row-within-tile
    const int q    = lane >> 4;   // quad index (k-group / C-row-group)
    const int b0   = blockIdx.x * GB;
    const int row0 = 16 * wid + 4 * q;   // tile-wave C rows row0..row0+3

    for (int i = tid; i < RESPLEN; i += 512) resp_s[i] = resp[i];
    for (int i = tid; i < NCH; i += 512) {
        float lam = sigwl[i];
        sigf[i]   = 299792458.0f / lam;
        siginv[i] = lam * 3.3356409519815204e-09f;   // lam/C0
    }
    if (tid < GB * NPUMP) {
        const int cc = tid >> 2, p = tid & 3;
        float lam = x[(b0 + cc) * 8 + p];
        pf[cc][p]   = 299792458.0f / lam;
        pinv[cc][p] = lam * 3.3356409519815204e-09f;
        ppw[cc][p]  = fabsf(x[(b0 + cc) * 8 + NPUMP + p]);
    }
    {   // zero both P buffers (incl. pad rows; pads are never rewritten)
        f16* pz = (f16*)Pls;
        for (int i = tid; i < 2 * GB * ROWSTR; i += 512) pz[i] = (f16)0.0f;
    }
    __syncthreads();

    // ---- A fragments: shared signal-signal gain block (fp16, x256) ----
    // v_mfma_f32_16x16x32_f16: A[row][k]: row = lane%16, k = 8*(lane/16)+j
    f16x8 Af0, Af1, Af2, Af3;
    f16x2 gp01[4], gp23[4];
    if (wid < 7) {
        const int arow = 16 * wid + c;
        const float fi = (arow < NCH) ? sigf[arow] : 0.0f;
        f16x8 af[4];
        #pragma unroll
        for (int t = 0; t < 4; ++t) {
            f16x8 a;
            #pragma unroll
            for (int j = 0; j < 8; ++j) {
                const int k = 32 * t + 8 * q + j;
                float v = 0.0f;
                // pump columns (k>=100) excluded: added via gp01/gp23 dot2s
                if (arow < NCH && k < NCH)
                    v = gentry(fi, sigf[k], siginv[k], resp_s);
                a[j] = (f16)v;
            }
            af[t] = a;
        }
        Af0 = af[0]; Af1 = af[1]; Af2 = af[2]; Af3 = af[3];

        // G_sp: batch-specific pump columns for owned C elements
        // C/D: col = lane&15 (=batch c), row = row0 + m
        #pragma unroll
        for (int m = 0; m < 4; ++m) {
            const int row = row0 + m;
            float v0 = 0.0f, v1 = 0.0f, v2 = 0.0f, v3 = 0.0f;
            if (row < NCH) {
                const float fi2 = sigf[row];
                v0 = gentry(fi2, pf[c][0], pinv[c][0], resp_s);
                v1 = gentry(fi2, pf[c][1], pinv[c][1], resp_s);
                v2 = gentry(fi2, pf[c][2], pinv[c][2], resp_s);
                v3 = gentry(fi2, pf[c][3], pinv[c][3], resp_s);
            }
            gp01[m] = f16x2{(f16)v0, (f16)v1};
            gp23[m] = f16x2{(f16)v2, (f16)v3};
        }
    }

    // ---- pump-row gain vectors (wave 7: lane (c,q) -> pump row q, batch c)
    f16x2 gpr[52];
    float P0p = 0.0f, sp = 0.0f, kps = 0.0f;
    if (wid == 7) {
        const float fi = pf[c][q];
        #pragma unroll
        for (int d = 0; d < 52; ++d) {
            const int j0 = 2 * d, j1 = 2 * d + 1;
            float f0 = (j0 < NCH) ? sigf[j0]   : pf[c][j0 - NCH];
            float w0 = (j0 < NCH) ? siginv[j0] : pinv[c][j0 - NCH];
            float f1 = (j1 < NCH) ? sigf[j1]   : pf[c][j1 - NCH];
            float w1 = (j1 < NCH) ? siginv[j1] : pinv[c][j1 - NCH];
            gpr[d] = f16x2{(f16)gentry(fi, f0, w0, resp_s),
                           (f16)gentry(fi, f1, w1, resp_s)};
        }
        P0p = ppw[c][q];
        sp  = P0p;
    }

    // ---- state init (f32, C-layout) + initial P into buffer 0 ----
    float P0v[4], sv[4], ks[4];
    #pragma unroll
    for (int m = 0; m < 4; ++m) {
        const int row = row0 + m;
        P0v[m] = (wid < 7 && row < NCH) ? 1.0e-3f : 0.0f;
        sv[m]  = P0v[m];
        ks[m]  = 0.0f;
    }

    int buf = 0;
    if (wid < 7 && row0 < NCH) {
        union { f16x2 h[2]; uint2 u2; } cv;
        cv.h[0] = f16x2{(f16)sv[0], (f16)sv[1]};
        cv.h[1] = f16x2{(f16)sv[2], (f16)sv[3]};
        *(uint2*)&Pls[0][c][row0] = cv.u2;
    }
    if (wid == 7) Pls[0][c][NCH + q] = (f16)sp;
    __syncthreads();

    // ---- RK4 main loop: 32 steps x 4 stages, 1 barrier per stage ----
    #pragma unroll 1
    for (int step = 0; step < NSTEPS; ++step) {
        STAGE(HDZ_F, 1.0f, 1, 0)   // k1
        STAGE(HDZ_F, 2.0f, 0, 0)   // k2
        STAGE(DZ_F,  2.0f, 0, 0)   // k3
        STAGE(0.0f,  1.0f, 0, 1)   // k4 + P0 += dz/6 * ksum
    }

    // ---- output: signal rows 0..99 (float4, 16B-aligned: 400 = 25*16) ----
    if (wid < 7 && row0 < NCH) {
        float4 o = make_float4(P0v[0], P0v[1], P0v[2], P0v[3]);
        *(float4*)&out[(b0 + c) * NCH + row0] = o;
    }
}

extern "C" void kernel_launch(void* const* d_in, const int* in_sizes, int n_in,
                              void* d_out, int out_size, void* d_ws, size_t ws_size,
                              hipStream_t stream)
{
    const float* x     = (const float*)d_in[0];
    const float* resp  = (const float*)d_in[1];
    const float* sigwl = (const float*)d_in[2];
    float* out = (float*)d_out;
    raman_kernel<<<BATCH / GB, 512, 0, stream>>>(x, resp, sigwl, out);
}